// Round 3
// baseline (105.112 us; speedup 1.0000x reference)
//
#include <hip/hip_runtime.h>
#include <math.h>

// Problem: B=16, N=512, F=256.
// Live computation only (attention matrix is dead code in the reference):
//   h       = x @ W_w^T + W_b                      [B,N,F]   (bf16 MFMA)
//   h_prime = leaky_relu(adj @ h, 0.2)             [B,N,F]   (sparse gather, h bf16)
//   g       = [x, h_prime] @ gate_w^T + gate_b     [B,N,1]
//   out     = sigmoid(g)*x + (1-sigmoid(g))*h_prime
//
// NOTE: measured dur includes ~60-85 us of harness reset (256 MB ws re-poison
// fill at ~45 us dominates) — our controllable budget is only the two kernels.

#define BATCH 16
#define NNODE 512
#define FDIM  256
#define M_TOT (BATCH * NNODE)   // 8192

typedef __bf16 bf16x8 __attribute__((ext_vector_type(8)));
typedef float  f32x4  __attribute__((ext_vector_type(4)));

static __device__ __forceinline__ unsigned short f2bf(float f) {
    union { float f; unsigned int i; } v; v.f = f;
    unsigned int r = v.i + 0x7FFFu + ((v.i >> 16) & 1u);   // RNE
    return (unsigned short)(r >> 16);
}
static __device__ __forceinline__ float bf2f(unsigned short u) {
    union { unsigned int i; float f; } v; v.i = ((unsigned int)u) << 16;
    return v.f;
}

// ---------------- Kernel 1: h = x @ W^T + bias  (bf16 MFMA) ----------------
// M=8192, N=256, K=256. BM=64, BN=64, BK=64 -> 512 blocks (2/CU, 8 waves/CU).
// Wave w computes rows [w*16, w*16+16) x 64 cols (4 col-tiles of 16).
// LDS row stride 72 bf16 = 36 dwords = 9 bank-groups (odd) => every 8-lane
// b128 phase covers all 8 bank groups => conflict-free.
#define BK 64
#define ASTR 72

__global__ __launch_bounds__(256) void h_gemm_mfma(const float* __restrict__ x,
                                                   const float* __restrict__ W,
                                                   const float* __restrict__ bias,
                                                   unsigned short* __restrict__ h) {
    __shared__ unsigned short As[64 * ASTR];   // 9216 B
    __shared__ unsigned short Bs[64 * ASTR];   // 9216 B

    const int t    = threadIdx.x;
    const int wave = t >> 6;
    const int lane = t & 63;
    const int ln   = lane & 15;
    const int quad = lane >> 4;
    const int m0   = (int)(blockIdx.x >> 2) * 64;   // 128 m-tiles
    const int n0   = (int)(blockIdx.x & 3) * 64;    // 4 n-tiles
    const int mA   = wave * 16;

    f32x4 acc[4] = {};

    for (int k0 = 0; k0 < FDIM; k0 += BK) {
        // Stage A and B: each 64x64 f32 -> bf16; 1024 float4 each, 4/thread.
#pragma unroll
        for (int i = 0; i < 4; i++) {
            int fid = i * 256 + t;
            int row = fid >> 4;
            int c4  = (fid & 15) * 4;
            float4 va = *(const float4*)(x + (size_t)(m0 + row) * FDIM + k0 + c4);
            ushort4 ba;
            ba.x = f2bf(va.x); ba.y = f2bf(va.y); ba.z = f2bf(va.z); ba.w = f2bf(va.w);
            *(ushort4*)&As[row * ASTR + c4] = ba;
            float4 vb = *(const float4*)(W + (size_t)(n0 + row) * FDIM + k0 + c4);
            ushort4 bb;
            bb.x = f2bf(vb.x); bb.y = f2bf(vb.y); bb.z = f2bf(vb.z); bb.w = f2bf(vb.w);
            *(ushort4*)&Bs[row * ASTR + c4] = bb;
        }
        __syncthreads();

#pragma unroll
        for (int ks = 0; ks < BK; ks += 32) {
            const int kb = ks + quad * 8;
            bf16x8 a0 = *(const bf16x8*)&As[(mA + ln) * ASTR + kb];
            bf16x8 b0 = *(const bf16x8*)&Bs[(0  + ln) * ASTR + kb];
            bf16x8 b1 = *(const bf16x8*)&Bs[(16 + ln) * ASTR + kb];
            bf16x8 b2 = *(const bf16x8*)&Bs[(32 + ln) * ASTR + kb];
            bf16x8 b3 = *(const bf16x8*)&Bs[(48 + ln) * ASTR + kb];
            acc[0] = __builtin_amdgcn_mfma_f32_16x16x32_bf16(a0, b0, acc[0], 0, 0, 0);
            acc[1] = __builtin_amdgcn_mfma_f32_16x16x32_bf16(a0, b1, acc[1], 0, 0, 0);
            acc[2] = __builtin_amdgcn_mfma_f32_16x16x32_bf16(a0, b2, acc[2], 0, 0, 0);
            acc[3] = __builtin_amdgcn_mfma_f32_16x16x32_bf16(a0, b3, acc[3], 0, 0, 0);
        }
        __syncthreads();
    }

    // Epilogue: D[row][col], col = lane&15, row = quad*4 + reg. Add bias, store bf16.
    const int mbase = m0 + mA + quad * 4;
#pragma unroll
    for (int j = 0; j < 4; j++) {
        const int gn = n0 + j * 16 + ln;
        const float bv = bias[gn];
        f32x4 c = acc[j];
#pragma unroll
        for (int r = 0; r < 4; r++) {
            h[(size_t)(mbase + r) * FDIM + gn] = f2bf(c[r] + bv);
        }
    }
}

// ---------------- Kernel 2: sparse aggregate + gate + blend ----------------
// One block (256 threads = 4 waves) per output row (b,i). adj ~5% dense binary.
// Wave w handles neighbors p = w, w+4, ...; each lane owns 4 consecutive
// bf16 columns (ushort4 = 8B/lane loads, 512 B/wave). Cross-wave partials
// reduced via LDS.
__global__ __launch_bounds__(256) void agg_gate(const float* __restrict__ adj,
                                                const float* __restrict__ x,
                                                const unsigned short* __restrict__ h,
                                                const float* __restrict__ gw,
                                                const float* __restrict__ gb,
                                                float* __restrict__ out) {
    __shared__ int   lst[NNODE];
    __shared__ int   cnt;
    __shared__ float pSum[4][FDIM];
    __shared__ float red[4];
    __shared__ float coeff_s;

    const int t  = threadIdx.x;
    const int w  = t >> 6;
    const int l  = t & 63;
    const int bi = blockIdx.x;      // 0..8191
    const int b  = bi >> 9;

    if (t == 0) cnt = 0;
    __syncthreads();

    // Compact nonzero column indices of adj row into LDS.
    const float* arow = adj + (size_t)bi * NNODE;
    float2 av = *(const float2*)(arow + 2 * t);
    if (av.x != 0.0f) { int p = atomicAdd(&cnt, 1); lst[p] = 2 * t; }
    if (av.y != 0.0f) { int p = atomicAdd(&cnt, 1); lst[p] = 2 * t + 1; }

    const float xv = x[(size_t)bi * FDIM + t];   // overlap with compaction
    __syncthreads();

    const int n = cnt;
    const unsigned short* hb = h + (size_t)b * NNODE * FDIM;

    // Neighbor-parallel gather: wave w takes p = w, w+4, ..., 2x unrolled.
    float4 s0 = {0.f, 0.f, 0.f, 0.f}, s1 = {0.f, 0.f, 0.f, 0.f};
    int p = w;
    for (; p + 4 < n; p += 8) {
        int j0 = lst[p];
        int j1 = lst[p + 4];
        ushort4 v0 = *(const ushort4*)(hb + (size_t)j0 * FDIM + 4 * l);
        ushort4 v1 = *(const ushort4*)(hb + (size_t)j1 * FDIM + 4 * l);
        s0.x += bf2f(v0.x); s0.y += bf2f(v0.y); s0.z += bf2f(v0.z); s0.w += bf2f(v0.w);
        s1.x += bf2f(v1.x); s1.y += bf2f(v1.y); s1.z += bf2f(v1.z); s1.w += bf2f(v1.w);
    }
    if (p < n) {
        int j0 = lst[p];
        ushort4 v0 = *(const ushort4*)(hb + (size_t)j0 * FDIM + 4 * l);
        s0.x += bf2f(v0.x); s0.y += bf2f(v0.y); s0.z += bf2f(v0.z); s0.w += bf2f(v0.w);
    }
    float4 s;
    s.x = s0.x + s1.x; s.y = s0.y + s1.y; s.z = s0.z + s1.z; s.w = s0.w + s1.w;
    *(float4*)&pSum[w][4 * l] = s;
    __syncthreads();

    // Thread t owns column t from here on.
    float sum = pSum[0][t] + pSum[1][t] + pSum[2][t] + pSum[3][t];
    float hp  = (sum > 0.0f) ? sum : 0.2f * sum;   // leaky_relu 0.2

    // gate: g = x . gw[0:256] + hp . gw[256:512] + gb
    float partial = xv * gw[t] + hp * gw[FDIM + t];
#pragma unroll
    for (int off = 32; off > 0; off >>= 1) partial += __shfl_down(partial, off);
    if (l == 0) red[w] = partial;
    __syncthreads();
    if (t == 0) {
        float g = red[0] + red[1] + red[2] + red[3] + gb[0];
        coeff_s = 1.0f / (1.0f + expf(-g));
    }
    __syncthreads();

    float c = coeff_s;
    out[(size_t)bi * FDIM + t] = c * xv + (1.0f - c) * hp;
}

extern "C" void kernel_launch(void* const* d_in, const int* in_sizes, int n_in,
                              void* d_out, int out_size, void* d_ws, size_t ws_size,
                              hipStream_t stream) {
    const float* x    = (const float*)d_in[0];
    const float* adj  = (const float*)d_in[1];
    const float* W_w  = (const float*)d_in[2];
    const float* W_b  = (const float*)d_in[3];
    // d_in[4] = A  (dead code in reference, unused)
    const float* gw   = (const float*)d_in[5];
    const float* gb   = (const float*)d_in[6];
    float* out = (float*)d_out;
    unsigned short* h = (unsigned short*)d_ws;   // 8192*256 bf16 = 4 MB scratch

    h_gemm_mfma<<<dim3(512), dim3(256), 0, stream>>>(x, W_w, W_b, h);
    agg_gate<<<dim3(M_TOT), dim3(256), 0, stream>>>(adj, x, h, gw, gb, out);
}